// Round 3
// baseline (1698.468 us; speedup 1.0000x reference)
//
#include <hip/hip_runtime.h>
#include <hip/hip_bf16.h>

typedef __bf16 bf16_t;
typedef __bf16 bf16x4 __attribute__((ext_vector_type(4)));
typedef __bf16 bf16x8 __attribute__((ext_vector_type(8)));
typedef float f32x4 __attribute__((ext_vector_type(4)));

#define B_ 32
#define N_ 16384
#define C_ 256
#define D_ 64
#define ROWS_TOTAL (B_ * N_)  // 524288

__device__ inline float wave_sum64(float v) {
#pragma unroll
  for (int o = 1; o < 64; o <<= 1) v += __shfl_xor(v, o);
  return v;
}

__device__ inline float half_sum32(float v) {
#pragma unroll
  for (int o = 1; o < 32; o <<= 1) v += __shfl_xor(v, o);
  return v;
}

__device__ inline float sigmoidf_(float x) { return 1.0f / (1.0f + __expf(-x)); }
__device__ inline float tanhf_(float x) { return 1.0f - 2.0f / (__expf(2.0f * x) + 1.0f); }

// ---------------------------------------------------------------------------
// prep: Wb = [Wk|Wv] in MFMA B-frag layout; GRU weight transposes; g init;
// zero per-iteration acc/wsum/cnt buffers. grid 451 x 256 = 115456 tasks.
// ---------------------------------------------------------------------------
__global__ __launch_bounds__(256) void prep_kernel(
    const float* __restrict__ Wk, const float* __restrict__ Wv,
    const float* __restrict__ Wih, const float* __restrict__ Whh,
    const float* __restrict__ slots, bf16_t* __restrict__ Wb,
    float* __restrict__ WihT, float* __restrict__ WhhT, float* __restrict__ g,
    float* __restrict__ accz, float* __restrict__ wsz, int* __restrict__ cnt) {
  int i = blockIdx.x * 256 + threadIdx.x;
  if (i < 32768) {
    int j = i & 7, l = (i >> 3) & 63, t = (i >> 9) & 7, kb = i >> 12;
    int k = kb * 32 + (l >> 4) * 8 + j;
    int n = t * 16 + (l & 15);
    float v = (n < 64) ? Wk[k * 64 + n] : Wv[k * 64 + (n - 64)];
    Wb[i] = (bf16_t)v;
  } else if (i < 45056) {
    int idx = i - 32768;
    int c = idx / 192, j = idx % 192;
    WihT[idx] = Wih[j * 64 + c];
  } else if (i < 57344) {
    int idx = i - 45056;
    int c = idx / 192, j = idx % 192;
    WhhT[idx] = Whh[j * 64 + c];
  } else if (i < 71680) {
    int idx = i - 57344;
    g[idx] = slots[idx];
  } else if (i < 114688) {  // 3 * 14336 acc floats
    accz[i - 71680] = 0.0f;
  } else if (i < 115360) {  // 3 * 224 wsum floats
    wsz[i - 114688] = 0.0f;
  } else if (i < 115456) {  // 3 * 32 counters
    cnt[i - 115360] = 0;
  }
}

// ---------------------------------------------------------------------------
// proj_ln v3: 256 threads (4 waves), 128-row tile, 64 KB LDS (2 blocks/CU).
// Phase 1: wave w rows w*32..+31, 4 rows/iter (16 lanes/row). Phase 2: wave
// handles TWO 16-row m-tiles -> 8 B-frag loads amortized over 16 MFMA per kb
// (halves Wb L2 traffic vs 1 m-tile/wave). Swizzle: unit r*32 + (c8 ^ (r&31)).
// ---------------------------------------------------------------------------
__global__ __launch_bounds__(256) void proj_ln_kernel(
    const float* __restrict__ inp, const float* __restrict__ lng,
    const float* __restrict__ lnb, const bf16_t* __restrict__ Wb,
    bf16_t* __restrict__ kbuf, bf16_t* __restrict__ vbuf) {
  __shared__ bf16_t xs[128 * 256];  // 64 KB
  const int tid = threadIdx.x, w = tid >> 6, lane = tid & 63;
  const int q4 = lane >> 4, lp = lane & 15;
  const long row0 = (long)blockIdx.x * 128;

  float4 gv[4], bv[4];
#pragma unroll
  for (int j = 0; j < 4; ++j) {
    gv[j] = *(const float4*)(lng + lp * 16 + j * 4);
    bv[j] = *(const float4*)(lnb + lp * 16 + j * 4);
  }

  // Phase 1: wave w -> rows w*32 .. w*32+31
#pragma unroll
  for (int i = 0; i < 8; ++i) {
    int r = w * 32 + i * 4 + q4;
    const float* rp = inp + (row0 + r) * C_ + lp * 16;
    float4 x0 = *(const float4*)(rp);
    float4 x1 = *(const float4*)(rp + 4);
    float4 x2 = *(const float4*)(rp + 8);
    float4 x3 = *(const float4*)(rp + 12);
    float s = (x0.x + x0.y + x0.z + x0.w) + (x1.x + x1.y + x1.z + x1.w) +
              (x2.x + x2.y + x2.z + x2.w) + (x3.x + x3.y + x3.z + x3.w);
    float s2 = (x0.x * x0.x + x0.y * x0.y + x0.z * x0.z + x0.w * x0.w) +
               (x1.x * x1.x + x1.y * x1.y + x1.z * x1.z + x1.w * x1.w) +
               (x2.x * x2.x + x2.y * x2.y + x2.z * x2.z + x2.w * x2.w) +
               (x3.x * x3.x + x3.y * x3.y + x3.z * x3.z + x3.w * x3.w);
#pragma unroll
    for (int o = 1; o < 16; o <<= 1) {
      s += __shfl_xor(s, o);
      s2 += __shfl_xor(s2, o);
    }
    float mean = s * (1.0f / 256.0f);
    float var = s2 * (1.0f / 256.0f) - mean * mean;
    float rstd = rsqrtf(var + 1e-5f);
    bf16x8 y0, y1;
    y0[0] = (bf16_t)((x0.x - mean) * rstd * gv[0].x + bv[0].x);
    y0[1] = (bf16_t)((x0.y - mean) * rstd * gv[0].y + bv[0].y);
    y0[2] = (bf16_t)((x0.z - mean) * rstd * gv[0].z + bv[0].z);
    y0[3] = (bf16_t)((x0.w - mean) * rstd * gv[0].w + bv[0].w);
    y0[4] = (bf16_t)((x1.x - mean) * rstd * gv[1].x + bv[1].x);
    y0[5] = (bf16_t)((x1.y - mean) * rstd * gv[1].y + bv[1].y);
    y0[6] = (bf16_t)((x1.z - mean) * rstd * gv[1].z + bv[1].z);
    y0[7] = (bf16_t)((x1.w - mean) * rstd * gv[1].w + bv[1].w);
    y1[0] = (bf16_t)((x2.x - mean) * rstd * gv[2].x + bv[2].x);
    y1[1] = (bf16_t)((x2.y - mean) * rstd * gv[2].y + bv[2].y);
    y1[2] = (bf16_t)((x2.z - mean) * rstd * gv[2].z + bv[2].z);
    y1[3] = (bf16_t)((x2.w - mean) * rstd * gv[2].w + bv[2].w);
    y1[4] = (bf16_t)((x3.x - mean) * rstd * gv[3].x + bv[3].x);
    y1[5] = (bf16_t)((x3.y - mean) * rstd * gv[3].y + bv[3].y);
    y1[6] = (bf16_t)((x3.z - mean) * rstd * gv[3].z + bv[3].z);
    y1[7] = (bf16_t)((x3.w - mean) * rstd * gv[3].w + bv[3].w);
    int base = r * 32, swz = r & 31;
    *(bf16x8*)(xs + (size_t)(base + ((2 * lp) ^ swz)) * 8) = y0;
    *(bf16x8*)(xs + (size_t)(base + ((2 * lp + 1) ^ swz)) * 8) = y1;
  }
  __syncthreads();

  // Phase 2: wave w -> rows w*32..w*32+31 as two 16-row m-tiles
  f32x4 acc[2][8];
  const f32x4 zf = {0.0f, 0.0f, 0.0f, 0.0f};
#pragma unroll
  for (int mt = 0; mt < 2; ++mt)
#pragma unroll
    for (int t = 0; t < 8; ++t) acc[mt][t] = zf;

  const int r0 = w * 32 + lp, r1 = r0 + 16;
  const int sw0 = r0 & 31, sw1 = r1 & 31;
  for (int kb = 0; kb < 8; ++kb) {
    bf16x8 a0 = *(const bf16x8*)(xs + (size_t)(r0 * 32 + ((kb * 4 + q4) ^ sw0)) * 8);
    bf16x8 a1 = *(const bf16x8*)(xs + (size_t)(r1 * 32 + ((kb * 4 + q4) ^ sw1)) * 8);
#pragma unroll
    for (int t = 0; t < 8; ++t) {
      bf16x8 bfr = *(const bf16x8*)(Wb + (size_t)((kb * 8 + t) * 64 + lane) * 8);
      acc[0][t] = __builtin_amdgcn_mfma_f32_16x16x32_bf16(a0, bfr, acc[0][t], 0, 0, 0);
      acc[1][t] = __builtin_amdgcn_mfma_f32_16x16x32_bf16(a1, bfr, acc[1][t], 0, 0, 0);
    }
  }

#pragma unroll
  for (int mt = 0; mt < 2; ++mt) {
#pragma unroll
    for (int t = 0; t < 8; ++t) {
      bf16_t* dst = (t < 4) ? kbuf : vbuf;
      int c = (t & 3) * 16 + lp;
#pragma unroll
      for (int reg = 0; reg < 4; ++reg) {
        long gr = row0 + w * 32 + mt * 16 + q4 * 4 + reg;
        dst[gr * 64 + c] = (bf16_t)acc[mt][t][reg];
      }
    }
  }
}

// ---------------------------------------------------------------------------
// qk: iteration-0 q = LN(g) @ Wq/bWq. grid 224 x 64.
// ---------------------------------------------------------------------------
__global__ __launch_bounds__(64) void qk_kernel(
    const float* __restrict__ g, const float* __restrict__ qg,
    const float* __restrict__ qb, const float* __restrict__ Wq,
    const float* __restrict__ bqg, const float* __restrict__ bqb,
    const float* __restrict__ bWq, float* __restrict__ q) {
  __shared__ float sx[64];
  int bid = blockIdx.x, lane = threadIdx.x;
  int m = bid % 7;
  const float* lng = (m < 6) ? qg : bqg;
  const float* lnb = (m < 6) ? qb : bqb;
  const float* W = (m < 6) ? Wq : bWq;
  float gvv = g[bid * 64 + lane];
  float s = wave_sum64(gvv);
  float s2 = wave_sum64(gvv * gvv);
  float mean = s * (1.0f / 64.0f);
  float var = s2 * (1.0f / 64.0f) - mean * mean;
  float rstd = rsqrtf(var + 1e-5f);
  sx[lane] = (gvv - mean) * rstd * lng[lane] + lnb[lane];
  __syncthreads();
  float qd = 0.0f;
#pragma unroll 8
  for (int c = 0; c < 64; ++c) qd += sx[c] * W[c * 64 + lane];
  q[bid * 64 + lane] = qd;
}

// ---------------------------------------------------------------------------
// attend_update: attention accumulation; the LAST block per batch b (atomic
// counter) then runs the GRU+MLP update for b's 7 slots and (optionally) the
// next-iteration q projection. grid 1024 x 256, one b per 32 blocks.
// acc/wsum/cnt are per-iteration buffers pre-zeroed by prep.
// ---------------------------------------------------------------------------
__global__ __launch_bounds__(256) void attend_update_kernel(
    const bf16_t* __restrict__ kbuf, const bf16_t* __restrict__ vbuf,
    const float* __restrict__ q, float* __restrict__ acc,
    float* __restrict__ wsum, int* __restrict__ cnt,
    const float* __restrict__ g, const float* __restrict__ WihT,
    const float* __restrict__ WhhT, const float* __restrict__ bih,
    const float* __restrict__ bhh, const float* __restrict__ mlg,
    const float* __restrict__ mlb, const float* __restrict__ mW1,
    const float* __restrict__ mb1, const float* __restrict__ mW2,
    const float* __restrict__ mb2, const float* __restrict__ bmlg,
    const float* __restrict__ bmlb, const float* __restrict__ bW1,
    const float* __restrict__ bb1, const float* __restrict__ bW2,
    const float* __restrict__ bb2, float* __restrict__ gout,
    const float* __restrict__ qg, const float* __restrict__ qb,
    const float* __restrict__ Wq, const float* __restrict__ bqg,
    const float* __restrict__ bqb, const float* __restrict__ bWq,
    float* __restrict__ qout, int write_q) {
  __shared__ float qs[448];
  __shared__ float s_acc[448];
  __shared__ float s_w[7];
  __shared__ int isLast;
  // update-phase scratch
  __shared__ float fuS[7][64], hpS[7][64], giS[7][192], ghS[7][192];
  __shared__ float xbS[7][64], a1S[7][128];

  int tid = threadIdx.x, w = tid >> 6, lane = tid & 63;
  int g4 = lane >> 4, lp = lane & 15;
  long chunk0 = (long)blockIdx.x * 512;
  int b = (int)(chunk0 >> 14);

  for (int idx = tid; idx < 448; idx += 256) {
    qs[idx] = q[b * 448 + idx];
    s_acc[idx] = 0.0f;
  }
  if (tid < 7) s_w[tid] = 0.0f;
  __syncthreads();

  float4 qv[7];
  const float4* qs4 = (const float4*)qs;
#pragma unroll
  for (int m = 0; m < 7; ++m) qv[m] = qs4[m * 16 + lp];

  float av[7][4];
  float wa[7];
#pragma unroll
  for (int m = 0; m < 7; ++m) {
    wa[m] = 0.0f;
#pragma unroll
    for (int j = 0; j < 4; ++j) av[m][j] = 0.0f;
  }

  for (int it = 0; it < 32; ++it) {
    long row = chunk0 + it * 16 + w * 4 + g4;
    bf16x4 kv = *(const bf16x4*)(kbuf + row * 64 + lp * 4);
    bf16x4 vv = *(const bf16x4*)(vbuf + row * 64 + lp * 4);
    float k0 = kv[0], k1 = kv[1], k2 = kv[2], k3 = kv[3];
    float lg[7];
#pragma unroll
    for (int m = 0; m < 7; ++m)
      lg[m] = k0 * qv[m].x + k1 * qv[m].y + k2 * qv[m].z + k3 * qv[m].w;
#pragma unroll
    for (int m = 0; m < 7; ++m) {
      lg[m] += __shfl_xor(lg[m], 1);
      lg[m] += __shfl_xor(lg[m], 2);
      lg[m] += __shfl_xor(lg[m], 4);
      lg[m] += __shfl_xor(lg[m], 8);
    }
    float mx = -1e30f;
#pragma unroll
    for (int m = 0; m < 7; ++m) {
      lg[m] *= 0.125f;
      mx = fmaxf(mx, lg[m]);
    }
    float e[7], s = 0.0f;
#pragma unroll
    for (int m = 0; m < 7; ++m) {
      e[m] = __expf(lg[m] - mx);
      s += e[m];
    }
    float inv = 1.0f / s;
    float v0 = vv[0], v1 = vv[1], v2 = vv[2], v3 = vv[3];
#pragma unroll
    for (int m = 0; m < 7; ++m) {
      float a = e[m] * inv + 1e-6f;
      wa[m] += a;
      av[m][0] += a * v0;
      av[m][1] += a * v1;
      av[m][2] += a * v2;
      av[m][3] += a * v3;
    }
  }

#pragma unroll
  for (int m = 0; m < 7; ++m) {
#pragma unroll
    for (int j = 0; j < 4; ++j) {
      av[m][j] += __shfl_xor(av[m][j], 16);
      av[m][j] += __shfl_xor(av[m][j], 32);
    }
    wa[m] += __shfl_xor(wa[m], 16);
    wa[m] += __shfl_xor(wa[m], 32);
  }
  if (g4 == 0) {
#pragma unroll
    for (int m = 0; m < 7; ++m)
#pragma unroll
      for (int j = 0; j < 4; ++j) atomicAdd(&s_acc[m * 64 + lp * 4 + j], av[m][j]);
  }
  if (lane == 0) {
#pragma unroll
    for (int m = 0; m < 7; ++m) atomicAdd(&s_w[m], wa[m]);
  }
  __syncthreads();
  for (int idx = tid; idx < 448; idx += 256) atomicAdd(&acc[b * 448 + idx], s_acc[idx]);
  if (tid < 7) atomicAdd(&wsum[b * 7 + tid], s_w[tid]);

  // --- last-block election ---
  if (tid == 0) {
    __threadfence();
    int old = atomicAdd(&cnt[b], 1);
    isLast = (old == 31) ? 1 : 0;
  }
  __syncthreads();
  if (!isLast) return;
  __threadfence();

  // --- update phase: 4 waves x 2 half-waves = slots 0..7 (slot 7 idle) ---
  int hw = lane >> 5, l32 = lane & 31;
  int m = w * 2 + hw;
  bool act = (m < 7);
  int bid = b * 7 + m;
  int d0 = l32 * 2, d1 = d0 + 1;

  const float *lg_, *lb_, *W1_, *b1_, *W2_, *b2_, *qlg_, *qlb_, *Wq_;
  if (m < 6) {
    lg_ = mlg; lb_ = mlb; W1_ = mW1; b1_ = mb1; W2_ = mW2; b2_ = mb2;
    qlg_ = qg; qlb_ = qb; Wq_ = Wq;
  } else {
    lg_ = bmlg; lb_ = bmlb; W1_ = bW1; b1_ = bb1; W2_ = bW2; b2_ = bb2;
    qlg_ = bqg; qlb_ = bqb; Wq_ = bWq;
  }

  if (act) {
    float wv = __hip_atomic_load(&wsum[bid], __ATOMIC_RELAXED, __HIP_MEMORY_SCOPE_AGENT);
    float a0 = __hip_atomic_load(&acc[bid * 64 + d0], __ATOMIC_RELAXED, __HIP_MEMORY_SCOPE_AGENT);
    float a1 = __hip_atomic_load(&acc[bid * 64 + d1], __ATOMIC_RELAXED, __HIP_MEMORY_SCOPE_AGENT);
    float inv = 1.0f / wv;
    fuS[m][d0] = a0 * inv;
    fuS[m][d1] = a1 * inv;
    hpS[m][d0] = g[bid * 64 + d0];
    hpS[m][d1] = g[bid * 64 + d1];
  }
  __syncthreads();

  if (act) {
#pragma unroll
    for (int t = 0; t < 6; ++t) {
      int j = l32 + 32 * t;
      float a = bih[j], bs = bhh[j];
      for (int c = 0; c < 64; ++c) {
        a += fuS[m][c] * WihT[c * 192 + j];
        bs += hpS[m][c] * WhhT[c * 192 + j];
      }
      giS[m][j] = a;
      ghS[m][j] = bs;
    }
  }
  __syncthreads();

  float h0 = 0.0f, h1 = 0.0f;
  if (act) {
    float r0 = sigmoidf_(giS[m][d0] + ghS[m][d0]);
    float z0 = sigmoidf_(giS[m][64 + d0] + ghS[m][64 + d0]);
    float n0 = tanhf_(giS[m][128 + d0] + r0 * ghS[m][128 + d0]);
    h0 = (1.0f - z0) * n0 + z0 * hpS[m][d0];
    float r1 = sigmoidf_(giS[m][d1] + ghS[m][d1]);
    float z1 = sigmoidf_(giS[m][64 + d1] + ghS[m][64 + d1]);
    float n1 = tanhf_(giS[m][128 + d1] + r1 * ghS[m][128 + d1]);
    h1 = (1.0f - z1) * n1 + z1 * hpS[m][d1];
    float s = half_sum32(h0 + h1);
    float s2 = half_sum32(h0 * h0 + h1 * h1);
    float mean = s * (1.0f / 64.0f);
    float var = s2 * (1.0f / 64.0f) - mean * mean;
    float rstd = rsqrtf(var + 1e-5f);
    xbS[m][d0] = (h0 - mean) * rstd * lg_[d0] + lb_[d0];
    xbS[m][d1] = (h1 - mean) * rstd * lg_[d1] + lb_[d1];
  }
  __syncthreads();

  if (act) {
#pragma unroll
    for (int t = 0; t < 4; ++t) {
      int j = l32 + 32 * t;
      float a = b1_[j];
      for (int c = 0; c < 64; ++c) a += xbS[m][c] * W1_[c * 128 + j];
      a1S[m][j] = fmaxf(a, 0.0f);
    }
  }
  __syncthreads();

  float res0 = 0.0f, res1 = 0.0f;
  if (act) {
    float o0 = b2_[d0], o1 = b2_[d1];
    for (int hh = 0; hh < 128; ++hh) {
      float a = a1S[m][hh];
      o0 += a * W2_[hh * 64 + d0];
      o1 += a * W2_[hh * 64 + d1];
    }
    res0 = h0 + o0;
    res1 = h1 + o1;
    gout[bid * 64 + d0] = res0;
    gout[bid * 64 + d1] = res1;
  }

  if (write_q) {
    if (act) {
      float s = half_sum32(res0 + res1);
      float s2 = half_sum32(res0 * res0 + res1 * res1);
      float mean = s * (1.0f / 64.0f);
      float var = s2 * (1.0f / 64.0f) - mean * mean;
      float rstd = rsqrtf(var + 1e-5f);
      xbS[m][d0] = (res0 - mean) * rstd * qlg_[d0] + qlb_[d0];
      xbS[m][d1] = (res1 - mean) * rstd * qlg_[d1] + qlb_[d1];
    }
    __syncthreads();
    if (act) {
      float q0 = 0.0f, q1 = 0.0f;
      for (int c = 0; c < 64; ++c) {
        float x = xbS[m][c];
        q0 += x * Wq_[c * 64 + d0];
        q1 += x * Wq_[c * 64 + d1];
      }
      qout[bid * 64 + d0] = q0;
      qout[bid * 64 + d1] = q1;
    }
  }
}

// ---------------------------------------------------------------------------
extern "C" void kernel_launch(void* const* d_in, const int* in_sizes, int n_in,
                              void* d_out, int out_size, void* d_ws, size_t ws_size,
                              hipStream_t stream) {
  const float* inputs   = (const float*)d_in[0];
  const float* slots_mu = (const float*)d_in[1];
  const float* ln_in_g  = (const float*)d_in[2];
  const float* ln_in_b  = (const float*)d_in[3];
  const float* Wk       = (const float*)d_in[4];
  const float* Wv       = (const float*)d_in[5];
  const float* q_ln_g   = (const float*)d_in[6];
  const float* q_ln_b   = (const float*)d_in[7];
  const float* Wq       = (const float*)d_in[8];
  const float* bq_ln_g  = (const float*)d_in[9];
  const float* bq_ln_b  = (const float*)d_in[10];
  const float* bWq      = (const float*)d_in[11];
  const float* gru_Wih  = (const float*)d_in[12];
  const float* gru_Whh  = (const float*)d_in[13];
  const float* gru_bih  = (const float*)d_in[14];
  const float* gru_bhh  = (const float*)d_in[15];
  const float* mlp_ln_g = (const float*)d_in[16];
  const float* mlp_ln_b = (const float*)d_in[17];
  const float* mlp_W1   = (const float*)d_in[18];
  const float* mlp_b1   = (const float*)d_in[19];
  const float* mlp_W2   = (const float*)d_in[20];
  const float* mlp_b2   = (const float*)d_in[21];
  const float* bmlp_ln_g = (const float*)d_in[22];
  const float* bmlp_ln_b = (const float*)d_in[23];
  const float* bmlp_W1  = (const float*)d_in[24];
  const float* bmlp_b1  = (const float*)d_in[25];
  const float* bmlp_W2  = (const float*)d_in[26];
  const float* bmlp_b2  = (const float*)d_in[27];
  float* out = (float*)d_out;

  char* ws = (char*)d_ws;
  size_t off = 0;
  const size_t KV_BYTES = (size_t)ROWS_TOTAL * 64 * 2;
  bf16_t* kbuf = (bf16_t*)(ws + off); off += KV_BYTES;
  bf16_t* vbuf = (bf16_t*)(ws + off); off += KV_BYTES;
  bf16_t* Wb   = (bf16_t*)(ws + off); off += 65536;
  float* WihT  = (float*)(ws + off);  off += 49152;
  float* WhhT  = (float*)(ws + off);  off += 49152;
  float* gbuf  = (float*)(ws + off);  off += 57344;
  float* qbuf  = (float*)(ws + off);  off += 57344;
  float* accb  = (float*)(ws + off);  off += 3 * 14336 * 4;  // per-iter acc
  float* wsumb = (float*)(ws + off);  off += 3 * 224 * 4;
  int*   cntb  = (int*)(ws + off);    off += 3 * 32 * 4;

  prep_kernel<<<451, 256, 0, stream>>>(Wk, Wv, gru_Wih, gru_Whh, slots_mu, Wb,
                                       WihT, WhhT, gbuf, accb, wsumb, cntb);
  proj_ln_kernel<<<ROWS_TOTAL / 128, 256, 0, stream>>>(inputs, ln_in_g, ln_in_b,
                                                       Wb, kbuf, vbuf);
  qk_kernel<<<224, 64, 0, stream>>>(gbuf, q_ln_g, q_ln_b, Wq, bq_ln_g, bq_ln_b,
                                    bWq, qbuf);
  for (int it = 0; it < 3; ++it) {
    attend_update_kernel<<<ROWS_TOTAL / 512, 256, 0, stream>>>(
        kbuf, vbuf, qbuf, accb + it * 14336, wsumb + it * 224, cntb + it * 32,
        gbuf, WihT, WhhT, gru_bih, gru_bhh, mlp_ln_g, mlp_ln_b, mlp_W1, mlp_b1,
        mlp_W2, mlp_b2, bmlp_ln_g, bmlp_ln_b, bmlp_W1, bmlp_b1, bmlp_W2,
        bmlp_b2, (it == 2) ? out : gbuf, q_ln_g, q_ln_b, Wq, bq_ln_g, bq_ln_b,
        bWq, qbuf, (it < 2) ? 1 : 0);
  }
}